// Round 5
// baseline (112.690 us; speedup 1.0000x reference)
//
#include <hip/hip_runtime.h>

// x: [8, 32, 32, 32, 32] fp32.  Flat = b*2^20 + i*32768 + j*1024 + k*32 + c
// W: [32, 256] row-major (o, 8 sections). Sections:
//   0:x 1:mean_i 2:mean_j 3:mean_k 4:mean_ij 5:mean_ik 6:mean_jk 7:mean_ijk
// out[b,i,j,k,o] = W0.x + B1[b,j,k,o] + B2[b,i,k,o] + A3[b,i,j,o]
//                + A12[b,k,o] + A13[b,j,o] + A23[b,i,o] + A123[b,o] + bias[o]
// R11: final/mid are latency-bound, and their xs LDS staging is pure added
// critical path: each x-row is consumed by 8 same-address lanes (HW merges),
// so stage NOTHING but the 4KB weight tile. final: LDS 21KB->4KB (8
// blocks/CU, 32 waves), no load-burst barrier; FMA loop reads x directly
// global->reg, 8 float4 loads in flight per 128 FMAs. mid GEMM: same
// structure, 96->192 blocks (128 rows each) + 24 pool blocks.
// reduce identical to R8 (verified).

static __device__ __forceinline__ float4 f4add(float4 a, float4 b) {
  a.x += b.x; a.y += b.y; a.z += b.z; a.w += b.w; return a;
}

__global__ __launch_bounds__(256) void reduce_kernel(
    const float* __restrict__ x, float* __restrict__ S1,
    float* __restrict__ S2, float* __restrict__ S3) {
  const int t = threadIdx.x;
  if (blockIdx.x < 256) {
    // seg0: S1[b, j=a, k, c] = sum_i x[b,i,a,k,c]; thread owns floats 4t..4t+3
    const int b = blockIdx.x >> 5, a = blockIdx.x & 31;
    const float* base = x + ((size_t)b << 20) + a * 1024 + 4 * t;
    float4 acc = make_float4(0.f, 0.f, 0.f, 0.f);
    #pragma unroll
    for (int i = 0; i < 32; ++i) acc = f4add(acc, *(const float4*)(base + i * 32768));
    ((float4*)(S1 + (size_t)(b * 32 + a) * 1024))[t] = acc;
  } else {
    // segA: block (b, i=a): stream slab x[b,a,:,:,:] once -> S2 row + S3 row
    __shared__ float sT[8 * 1028];   // 8 j-rows of [k,c] (1024) + 4 pad
    const int idx = blockIdx.x - 256;
    const int b = idx >> 5, a = idx & 31;
    const float* slab = x + ((size_t)b << 20) + a * 32768;
    float4 accS2 = make_float4(0.f, 0.f, 0.f, 0.f);
    const int jl = t >> 5, cc = t & 31;      // S3 role: (j_loc, c)
    float* s3row = S3 + (size_t)(b * 32 + a) * 1024;

    for (int jt = 0; jt < 4; ++jt) {
      // load 8 KB tile (j = 8*jt .. +7), fully coalesced float4
      const float4* src4 = (const float4*)(slab + jt * 8192);
      #pragma unroll
      for (int m = 0; m < 8; ++m) {
        const int q = t + 256 * m;           // float4 idx in tile
        const float4 v = src4[q];
        float* p = sT + (q >> 8) * 1028 + 4 * (q & 255);
        p[0] = v.x; p[1] = v.y; p[2] = v.z; p[3] = v.w;
      }
      __syncthreads();
      // S2 accumulate: thread owns (k,c) quad at 4t
      #pragma unroll
      for (int j = 0; j < 8; ++j)
        accS2 = f4add(accS2, *(const float4*)(sT + j * 1028 + 4 * t));
      // S3: thread (jl, cc) sums over k; banks (4*jl + cc + 32k)%32: 2-way free
      float s3 = 0.f;
      #pragma unroll
      for (int k = 0; k < 32; ++k) s3 += sT[jl * 1028 + k * 32 + cc];
      s3row[jt * 256 + t] = s3;              // j = 8*jt + jl, coalesced
      __syncthreads();
    }
    ((float4*)(S2 + (size_t)(b * 32 + a) * 1024))[t] = accS2;
  }
}

// blocks 0..191: three [8192x32]x[32x32] GEMMs, 128 rows/block, no x-LDS.
// blocks 192..215: second-level pools -> A12/A13/A23/A123 tables.
__global__ __launch_bounds__(256) void mid_kernel(
    const float* __restrict__ S1, const float* __restrict__ S2,
    const float* __restrict__ S3, const float* __restrict__ W,
    float* __restrict__ B1, float* __restrict__ B2, float* __restrict__ A3o,
    float* __restrict__ A12g, float* __restrict__ A13g,
    float* __restrict__ A23g, float* __restrict__ A123g,
    float* __restrict__ W0t) {
  __shared__ float smem[4096];
  const int t = threadIdx.x;
  if (blockIdx.x < 192) {
    float* wt = smem;            // W section seg+1 transposed [c*32+o]
    const int seg = blockIdx.x / 64;
    const int r0 = (blockIdx.x & 63) * 128;
    const float* src = (seg == 0) ? S1 : (seg == 1) ? S2 : S3;
    float* dst = (seg == 0) ? B1 : (seg == 1) ? B2 : A3o;

    #pragma unroll
    for (int m = 0; m < 4; ++m) {
      const int e = t + 256 * m;
      wt[e] = W[(e & 31) * 256 + (seg + 1) * 32 + (e >> 5)];
    }
    if (blockIdx.x == 0) {
      #pragma unroll
      for (int m = 0; m < 4; ++m) {
        const int e = t + 256 * m;
        W0t[e] = W[(e & 31) * 256 + (e >> 5)];   // W0t[c*32+o]
      }
    }
    __syncthreads();

    const int rg = t >> 3, og = t & 7;
    const int row0 = r0 + 4 * rg;
    const int oo = og * 4;
    float acc[4][4];
    #pragma unroll
    for (int r = 0; r < 4; ++r)
      #pragma unroll
      for (int u = 0; u < 4; ++u) acc[r][u] = 0.f;

    const float4* wt4 = (const float4*)wt;
    const float4* sr4 = (const float4*)(src + (size_t)row0 * 32);
    #pragma unroll
    for (int cb = 0; cb < 4; ++cb) {
      float xv[4][8];
      #pragma unroll
      for (int r = 0; r < 4; ++r) {
        const float4 a0 = sr4[r * 8 + cb * 2];
        const float4 a1 = sr4[r * 8 + cb * 2 + 1];
        xv[r][0] = a0.x; xv[r][1] = a0.y; xv[r][2] = a0.z; xv[r][3] = a0.w;
        xv[r][4] = a1.x; xv[r][5] = a1.y; xv[r][6] = a1.z; xv[r][7] = a1.w;
      }
      #pragma unroll
      for (int cc = 0; cc < 8; ++cc) {
        const float4 w = wt4[(cb * 8 + cc) * 8 + og];
        #pragma unroll
        for (int r = 0; r < 4; ++r) {
          acc[r][0] += xv[r][cc] * w.x; acc[r][1] += xv[r][cc] * w.y;
          acc[r][2] += xv[r][cc] * w.z; acc[r][3] += xv[r][cc] * w.w;
        }
      }
    }
    const float s = 1.f / 32.f;
    #pragma unroll
    for (int r = 0; r < 4; ++r) {
      *(float4*)(dst + (size_t)(row0 + r) * 32 + oo) =
          make_float4(acc[r][0] * s, acc[r][1] * s, acc[r][2] * s, acc[r][3] * s);
    }
  } else {
    // pool: blk = seg*8 + b
    const int blk = blockIdx.x - 192;
    const int seg = blk >> 3, b = blk & 7;
    float* sBuf  = smem;          // [32][32] second-level sums
    float* sW    = smem + 1024;   // section 4+seg transposed [c*32+o]
    float* sW7   = smem + 2048;   // section 7 transposed
    float* sS123 = smem + 3072;   // [32]
    const int sec = 4 + seg;

    #pragma unroll
    for (int m = 0; m < 4; ++m) {
      const int e = t + 256 * m, c = e >> 5, o = e & 31;
      sW[e] = W[o * 256 + sec * 32 + c];
      if (seg == 0) sW7[e] = W[o * 256 + 7 * 32 + c];
    }
    const float* Sb = ((seg == 2) ? S2 : S1) + (size_t)b * 32768;
    #pragma unroll
    for (int m = 0; m < 4; ++m) {
      const int e = t + 256 * m, a = e >> 5, c = e & 31;
      float s = 0.f;
      if (seg == 0) {            // S12[k=a,c] = sum_j S1[b,j,a,c]
        for (int j = 0; j < 32; ++j) s += Sb[j * 1024 + a * 32 + c];
      } else {                   // S13/S23[(j|i)=a,c] = sum_k
        for (int k = 0; k < 32; ++k) s += Sb[a * 1024 + k * 32 + c];
      }
      sBuf[e] = s;
    }
    __syncthreads();
    if (seg == 0 && t < 32) {
      float s = 0.f;
      for (int k = 0; k < 32; ++k) s += sBuf[k * 32 + t];
      sS123[t] = s;
    }
    __syncthreads();
    float* Ag = (seg == 0) ? A12g : (seg == 1) ? A13g : A23g;
    #pragma unroll
    for (int m = 0; m < 4; ++m) {
      const int e = t + 256 * m, a = e >> 5, o = e & 31;
      float s = 0.f;
      #pragma unroll
      for (int c = 0; c < 32; ++c) s += sW[c * 32 + o] * sBuf[a * 32 + c];
      Ag[b * 1024 + e] = s * (1.f / 1024.f);
    }
    if (seg == 0 && t < 32) {
      float s = 0.f;
      #pragma unroll
      for (int c = 0; c < 32; ++c) s += sW7[c * 32 + t] * sS123[c];
      A123g[b * 32 + t] = s * (1.f / 32768.f);
    }
  }
}

// 128 rows/block, 2048 blocks, LDS = 4KB (wt only) -> up to 8 blocks/CU.
// Thread = (rg=t>>3: 4 rows, og=t&7: 4 outs). x read global->reg in the
// FMA loop (8 og-lanes share each address; coalescer merges for free).
__global__ __launch_bounds__(256) void final_kernel(
    const float* __restrict__ x, const float* __restrict__ W0t,
    const float* __restrict__ B1, const float* __restrict__ B2,
    const float* __restrict__ A3o, const float* __restrict__ A12g,
    const float* __restrict__ A13g, const float* __restrict__ A23g,
    const float* __restrict__ A123g, const float* __restrict__ bias,
    float* __restrict__ out) {
  __shared__ float wt[1024];     // W0 transposed [c*32+o]
  const int t = threadIdx.x;
  const size_t pos0 = (size_t)blockIdx.x * 128;

  const int rg = t >> 3, og = t & 7;
  const int lrow0 = 4 * rg;
  const size_t p0 = pos0 + lrow0;
  const int k0 = (int)(p0 & 31), j = (int)(p0 >> 5) & 31,
            i = (int)(p0 >> 10) & 31, b = (int)(p0 >> 15);
  const int oo = og * 4;

  // issue row-invariant table loads first: latency hides under wt load + FMA
  const float4 va3  = *(const float4*)(A3o  + ((size_t)((b * 32 + i) * 32 + j)) * 32 + oo);
  const float4 va13 = *(const float4*)(A13g + (size_t)(b * 32 + j) * 32 + oo);
  const float4 va23 = *(const float4*)(A23g + (size_t)(b * 32 + i) * 32 + oo);
  const float4 va123= *(const float4*)(A123g + (size_t)b * 32 + oo);
  const float4 vbi  = *(const float4*)(bias + oo);

  #pragma unroll
  for (int m = 0; m < 4; ++m) wt[t + 256 * m] = W0t[t + 256 * m];
  __syncthreads();

  float acc[4][4];
  #pragma unroll
  for (int r = 0; r < 4; ++r)
    #pragma unroll
    for (int u = 0; u < 4; ++u) acc[r][u] = 0.f;

  const float4* wt4 = (const float4*)wt;
  const float4* xr4 = (const float4*)(x + p0 * 32);   // row r -> idx r*8 + q
  #pragma unroll
  for (int cb = 0; cb < 4; ++cb) {
    float xv[4][8];
    #pragma unroll
    for (int r = 0; r < 4; ++r) {
      const float4 a0 = xr4[r * 8 + cb * 2];
      const float4 a1 = xr4[r * 8 + cb * 2 + 1];
      xv[r][0] = a0.x; xv[r][1] = a0.y; xv[r][2] = a0.z; xv[r][3] = a0.w;
      xv[r][4] = a1.x; xv[r][5] = a1.y; xv[r][6] = a1.z; xv[r][7] = a1.w;
    }
    #pragma unroll
    for (int cc = 0; cc < 8; ++cc) {
      const float4 w = wt4[(cb * 8 + cc) * 8 + og];
      #pragma unroll
      for (int r = 0; r < 4; ++r) {
        acc[r][0] += xv[r][cc] * w.x; acc[r][1] += xv[r][cc] * w.y;
        acc[r][2] += xv[r][cc] * w.z; acc[r][3] += xv[r][cc] * w.w;
      }
    }
  }

  float inv[4];
  inv[0] = va3.x + va13.x + va23.x + va123.x + vbi.x;
  inv[1] = va3.y + va13.y + va23.y + va123.y + vbi.y;
  inv[2] = va3.z + va13.z + va23.z + va123.z + vbi.z;
  inv[3] = va3.w + va13.w + va23.w + va123.w + vbi.w;

  #pragma unroll
  for (int r = 0; r < 4; ++r) {
    const int k = k0 + r;
    const float4 vb1 = *(const float4*)(B1 + ((size_t)((b * 32 + j) * 32 + k)) * 32 + oo);
    const float4 vb2 = *(const float4*)(B2 + ((size_t)((b * 32 + i) * 32 + k)) * 32 + oo);
    const float4 v12 = *(const float4*)(A12g + (size_t)(b * 32 + k) * 32 + oo);
    acc[r][0] += inv[0] + vb1.x + vb2.x + v12.x;
    acc[r][1] += inv[1] + vb1.y + vb2.y + v12.y;
    acc[r][2] += inv[2] + vb1.z + vb2.z + v12.z;
    acc[r][3] += inv[3] + vb1.w + vb2.w + v12.w;
  }

  #pragma unroll
  for (int r = 0; r < 4; ++r) {
    *(float4*)(out + (p0 + r) * 32 + oo) =
        make_float4(acc[r][0], acc[r][1], acc[r][2], acc[r][3]);
  }
}

extern "C" void kernel_launch(void* const* d_in, const int* in_sizes, int n_in,
                              void* d_out, int out_size, void* d_ws, size_t ws_size,
                              hipStream_t stream) {
  const float* x    = (const float*)d_in[0];
  const float* W    = (const float*)d_in[1];
  const float* bias = (const float*)d_in[2];
  float* out = (float*)d_out;
  float* ws  = (float*)d_ws;
  float* S1    = ws;                // 262144
  float* S2    = ws + 262144;
  float* S3    = ws + 524288;
  float* B1    = ws + 786432;
  float* B2    = ws + 1048576;
  float* A3o   = ws + 1310720;
  float* W0t   = ws + 1572864;      // 1024
  float* A12g  = ws + 1573888;      // 8192
  float* A13g  = ws + 1582080;      // 8192
  float* A23g  = ws + 1590272;      // 8192
  float* A123g = ws + 1598464;      // 256

  reduce_kernel<<<512, 256, 0, stream>>>(x, S1, S2, S3);
  mid_kernel<<<216, 256, 0, stream>>>(S1, S2, S3, W, B1, B2, A3o,
                                      A12g, A13g, A23g, A123g, W0t);
  final_kernel<<<2048, 256, 0, stream>>>(x, W0t, B1, B2, A3o, A12g, A13g,
                                         A23g, A123g, bias, out);
}